// Round 5
// baseline (166.686 us; speedup 1.0000x reference)
//
#include <hip/hip_runtime.h>
#include <stdint.h>

#define S_LEN 2048
#define BATCH 2
#define DMODEL 1024
#define NHEAD 16
#define DHEAD 64
// softmax scale folded into Q projection, in exp2 domain: 1/8 * log2(e)
#define QSCALE 0.18033688011112042f

typedef float f32x4 __attribute__((ext_vector_type(4)));
typedef float f32x16 __attribute__((ext_vector_type(16)));
typedef __bf16 bf16x8 __attribute__((ext_vector_type(8)));

__device__ __forceinline__ unsigned short f2bf(float f) {
  union { float f; unsigned int u; } v;
  v.f = f;
  unsigned int u = v.u;
  return (unsigned short)((u + 0x7fffu + ((u >> 16) & 1u)) >> 16);
}

__device__ __forceinline__ unsigned pk2(float lo, float hi_) {
  union { __bf16 h[2]; unsigned u; } c;
  c.h[0] = (__bf16)lo; c.h[1] = (__bf16)hi_;
  return c.u;
}

__device__ __forceinline__ void gld16(const void* g, void* l) {
  __builtin_amdgcn_global_load_lds((__attribute__((address_space(1))) void*)(g),
                                   (__attribute__((address_space(3))) void*)(l),
                                   16, 0, 0);
}

// ---------------- fp32 -> bf16 pack (all 7 tensors, one launch) ----------------
__global__ void cvt_all_kernel(const float* __restrict__ q, const float* __restrict__ k,
                               const float* __restrict__ v, const float* __restrict__ wq,
                               const float* __restrict__ wk, const float* __restrict__ wv,
                               const float* __restrict__ wosrc, unsigned short* __restrict__ xp,
                               unsigned short* __restrict__ wp, unsigned short* __restrict__ wo) {
  const int b = blockIdx.x;
  const float* src;
  unsigned short* dst;
  if (b < 12288) {
    const int z = b >> 12;
    const int local = b & 4095;
    src = (z == 0 ? q : (z == 1 ? k : v)) + (size_t)local * 1024;
    dst = xp + (size_t)z * 4194304 + (size_t)local * 1024;
  } else {
    const int z = (b - 12288) >> 10;
    const int local = (b - 12288) & 1023;
    src = (z == 0 ? wq : (z == 1 ? wk : (z == 2 ? wv : wosrc))) + (size_t)local * 1024;
    dst = (z < 3 ? wp + (size_t)z * 1048576 : wo) + (size_t)local * 1024;
  }
  const int i = threadIdx.x * 4;
  const float4 val = *(const float4*)(src + i);
  ushort4 o;
  o.x = f2bf(val.x); o.y = f2bf(val.y); o.z = f2bf(val.z); o.w = f2bf(val.w);
  *(ushort4*)(dst + i) = o;
}

// ---------------- GEMM: C[m,n] = sum_k A[m,k]*W[n,k] (+bias) ----------------
// MODE 0: z selects Q/K/V; Q gets QSCALE folded in; scatter to qw/kw ([bh][s][dk]) / vtw ([bh][dk][s]).
// MODE 1: fp32 out + bias.
template <int MODE>
__global__ __launch_bounds__(256, 2) void gemm_bt(
    const unsigned short* __restrict__ Abase,
    const unsigned short* __restrict__ Wbase,
    const float* __restrict__ bias0, const float* __restrict__ bias1,
    const float* __restrict__ bias2,
    unsigned short* __restrict__ qw, unsigned short* __restrict__ kw,
    unsigned short* __restrict__ vtw, float* __restrict__ outp) {
  constexpr int M = S_LEN * BATCH;  // 4096
  constexpr int N = DMODEL;         // 1024
  constexpr int K = DMODEL;         // 1024
  __shared__ unsigned short At[128 * 32];
  __shared__ unsigned short Bt[128 * 32];

  const int m0 = blockIdx.x * 128;
  const int n0 = blockIdx.y * 128;
  const int z = (MODE == 0) ? blockIdx.z : 0;
  const unsigned short* A = Abase + (size_t)z * M * K;
  const unsigned short* W = Wbase + (size_t)z * N * K;
  const float* bias = (z == 0 ? bias0 : (z == 1 ? bias1 : bias2));

  const int tid = threadIdx.x;
  const int w = tid >> 6, l = tid & 63;
  const int wr = w >> 1, wc = w & 1;
  const int lr = l & 15, lg = l >> 4;

  const int srow = tid >> 2;       // 0..63
  const int scol = (tid & 3) * 8;  // element col within 32-wide k tile

  f32x4 acc[4][4] = {};

  for (int k0 = 0; k0 < K; k0 += 32) {
    {
      const unsigned short* ga0 = A + (size_t)(m0 + srow) * K + k0 + scol;
      const unsigned short* ga1 = A + (size_t)(m0 + 64 + srow) * K + k0 + scol;
      const unsigned short* gb0 = W + (size_t)(n0 + srow) * K + k0 + scol;
      const unsigned short* gb1 = W + (size_t)(n0 + 64 + srow) * K + k0 + scol;
      char* la = (char*)At + w * 1024;
      char* lb = (char*)Bt + w * 1024;
      gld16(ga0, la);
      gld16(ga1, la + 4096);
      gld16(gb0, lb);
      gld16(gb1, lb + 4096);
    }
    __syncthreads();
    bf16x8 af[4], bfr[4];
#pragma unroll
    for (int mt = 0; mt < 4; ++mt)
      af[mt] = *(const bf16x8*)&At[(wr * 64 + mt * 16 + lr) * 32 + lg * 8];
#pragma unroll
    for (int nt = 0; nt < 4; ++nt)
      bfr[nt] = *(const bf16x8*)&Bt[(wc * 64 + nt * 16 + lr) * 32 + lg * 8];
#pragma unroll
    for (int mt = 0; mt < 4; ++mt)
#pragma unroll
      for (int nt = 0; nt < 4; ++nt)
        acc[mt][nt] = __builtin_amdgcn_mfma_f32_16x16x32_bf16(af[mt], bfr[nt], acc[mt][nt], 0, 0, 0);
    __syncthreads();
  }

#pragma unroll
  for (int mt = 0; mt < 4; ++mt) {
#pragma unroll
    for (int nt = 0; nt < 4; ++nt) {
#pragma unroll
      for (int r = 0; r < 4; ++r) {
        const int gm = m0 + wr * 64 + mt * 16 + lg * 4 + r;
        const int gn = n0 + wc * 64 + nt * 16 + lr;
        float v = acc[mt][nt][r] + bias[gn];
        if (MODE == 1) {
          outp[(size_t)gm * N + gn] = v;
        } else {
          if (z == 0) v *= QSCALE;  // softmax scale + log2e (exp2-domain softmax)
          const int s = gm >> 1, bb = gm & 1;
          const int h = gn >> 6, dk = gn & 63;
          const int bh = bb * NHEAD + h;
          const unsigned short bv_ = f2bf(v);
          if (z == 0)
            qw[((size_t)bh * S_LEN + s) * DHEAD + dk] = bv_;
          else if (z == 1)
            kw[((size_t)bh * S_LEN + s) * DHEAD + dk] = bv_;
          else
            vtw[((size_t)bh * DHEAD + dk) * S_LEN + s] = bv_;
        }
      }
    }
  }
}

// ---------------- causal flash attention, swapped-operand 32x32 MFMA ----------------
// Balanced pairing: block (bh, x) sequentially processes q-tiles qtA=31-x then qtB=x
// -> every block does exactly 33 kv-tile iterations (no causal tail).
// Grid is bh-major so linear%8 = bh%8: each head's K/V pinned to one XCD's L2.
// Double-buffered K/V staging; exp2-domain softmax; in-register P^T build.
__global__ __launch_bounds__(128) void attn_kernel(
    const unsigned short* __restrict__ qw, const unsigned short* __restrict__ kw,
    const unsigned short* __restrict__ vtw, unsigned short* __restrict__ x2) {
  __shared__ unsigned short klds[2][4096];  // [buf][kv][d], 16B-chunk XOR swizzle by (row&7)
  __shared__ unsigned short vlds[2][4096];  // [buf][d][kv], same swizzle

  const int bh = blockIdx.x;             // 0..31 (XCD = bh%8)
  const int xpair = blockIdx.y;          // 0..15
  const int bb = bh >> 4, h = bh & 15;
  const int tid = threadIdx.x;
  const int w = tid >> 6, l = tid & 63;
  const int q5 = l & 31, hi = l >> 5;

  const size_t qkbase = (size_t)bh * S_LEN * DHEAD;
  const size_t vbase = (size_t)bh * DHEAD * S_LEN;

  const int qtA = 31 - xpair, qtB = xpair;
  const int nA = qtA + 1;
  const int nit = nA + qtB + 1;  // == 33

  auto stage = [&](int kt, int b) {
#pragma unroll
    for (int r = 0; r < 4; ++r) {
      const int id = r * 128 + tid;
      const int row = id >> 3;
      const int sw = (id & 7) ^ (row & 7);
      gld16(kw + qkbase + (size_t)(kt * 64 + row) * DHEAD + sw * 8,
            (char*)&klds[b][0] + r * 2048 + w * 1024);
      gld16(vtw + vbase + (size_t)row * S_LEN + kt * 64 + sw * 8,
            (char*)&vlds[b][0] + r * 2048 + w * 1024);
    }
  };

  // ---- phase state ----
  int qt = qtA;
  int qrow = qt * 64 + w * 32 + q5;
  bf16x8 qf[4];
#pragma unroll
  for (int d = 0; d < 4; ++d)
    qf[d] = *(const bf16x8*)&qw[qkbase + (size_t)qrow * DHEAD + d * 16 + hi * 8];

  f32x16 oacc0, oacc1;  // O^T[d = crow(r,hi) + 32*dh][q = q5]
#pragma unroll
  for (int r = 0; r < 16; ++r) { oacc0[r] = 0.f; oacc1[r] = 0.f; }
  float mrun = -1e30f, lrun = 0.f;

  auto flush = [&](int qr) {
    const float invl = 1.0f / lrun;
    const size_t obase = ((size_t)qr * BATCH + bb) * DMODEL + h * DHEAD;
#pragma unroll
    for (int g = 0; g < 4; ++g) {
      const int d0 = 8 * g + 4 * hi;
      ushort4 s0, s1;
      s0.x = f2bf(oacc0[4 * g + 0] * invl);
      s0.y = f2bf(oacc0[4 * g + 1] * invl);
      s0.z = f2bf(oacc0[4 * g + 2] * invl);
      s0.w = f2bf(oacc0[4 * g + 3] * invl);
      s1.x = f2bf(oacc1[4 * g + 0] * invl);
      s1.y = f2bf(oacc1[4 * g + 1] * invl);
      s1.z = f2bf(oacc1[4 * g + 2] * invl);
      s1.w = f2bf(oacc1[4 * g + 3] * invl);
      *(ushort4*)(x2 + obase + d0) = s0;
      *(ushort4*)(x2 + obase + 32 + d0) = s1;
    }
  };

  // prologue: stage phase-A tile 0 into buf 0
  stage(0, 0);
  __syncthreads();

  for (int i = 0; i < nit; ++i) {
    const int cur = i & 1;
    // prefetch next iter's K/V tile into the other buffer
    if (i + 1 < nit) {
      const int nk = (i + 1 < nA) ? (i + 1) : (i + 1 - nA);
      stage(nk, cur ^ 1);
    }
    const int kt = (i < nA) ? i : (i - nA);

    // ---- QK^T (swapped): S^T[kv][q], kv halves A(0-31)/B(32-63) ----
    f32x16 sA, sB;
#pragma unroll
    for (int r = 0; r < 16; ++r) { sA[r] = 0.f; sB[r] = 0.f; }
    __builtin_amdgcn_s_setprio(1);
#pragma unroll
    for (int d = 0; d < 4; ++d) {
      const int ch = (2 * d + hi) ^ (q5 & 7);
      const bf16x8 kfA = *(const bf16x8*)((const char*)&klds[cur][0] + q5 * 128 + ch * 16);
      const bf16x8 kfB = *(const bf16x8*)((const char*)&klds[cur][0] + (32 + q5) * 128 + ch * 16);
      sA = __builtin_amdgcn_mfma_f32_32x32x16_bf16(kfA, qf[d], sA, 0, 0, 0);
      sB = __builtin_amdgcn_mfma_f32_32x32x16_bf16(kfB, qf[d], sB, 0, 0, 0);
    }
    __builtin_amdgcn_s_setprio(0);

    if (kt == qt) {  // causal mask on diagonal tile; kv = crow(r,hi) (+32)
      const int qloc = w * 32 + q5;
#pragma unroll
      for (int r = 0; r < 16; ++r) {
        const int kv = (r & 3) + 8 * (r >> 2) + 4 * hi;
        if (kv > qloc) sA[r] = -1e9f;
        if (kv + 32 > qloc) sB[r] = -1e9f;
      }
    }

    // ---- online softmax (exp2 domain), tree reductions ----
    float mx[8];
#pragma unroll
    for (int j = 0; j < 8; ++j)
      mx[j] = fmaxf(fmaxf(sA[j], sA[j + 8]), fmaxf(sB[j], sB[j + 8]));
#pragma unroll
    for (int j = 0; j < 4; ++j) mx[j] = fmaxf(mx[j], mx[j + 4]);
    float tmax = fmaxf(fmaxf(mx[0], mx[1]), fmaxf(mx[2], mx[3]));
    tmax = fmaxf(tmax, __shfl_xor(tmax, 32, 64));  // merge disjoint kv halves
    const float mnew = fmaxf(mrun, tmax);
    const float resc = exp2f(mrun - mnew);
    mrun = mnew;
#pragma unroll
    for (int r = 0; r < 16; ++r) sA[r] = exp2f(sA[r] - mnew);
#pragma unroll
    for (int r = 0; r < 16; ++r) sB[r] = exp2f(sB[r] - mnew);
    float sm[8];
#pragma unroll
    for (int j = 0; j < 8; ++j)
      sm[j] = (sA[j] + sA[j + 8]) + (sB[j] + sB[j + 8]);
#pragma unroll
    for (int j = 0; j < 4; ++j) sm[j] += sm[j + 4];
    float rsum = (sm[0] + sm[1]) + (sm[2] + sm[3]);
    rsum += __shfl_xor(rsum, 32, 64);
    lrun = lrun * resc + rsum;
#pragma unroll
    for (int r = 0; r < 16; ++r) { oacc0[r] *= resc; oacc1[r] *= resc; }

    // ---- P^T B-frags in-register: bf16 pack + shfl_xor(32) exchange ----
    unsigned pk[2][8];
#pragma unroll
    for (int g = 0; g < 4; ++g) {
      pk[0][2 * g]     = pk2(sA[4 * g],     sA[4 * g + 1]);
      pk[0][2 * g + 1] = pk2(sA[4 * g + 2], sA[4 * g + 3]);
      pk[1][2 * g]     = pk2(sB[4 * g],     sB[4 * g + 1]);
      pk[1][2 * g + 1] = pk2(sB[4 * g + 2], sB[4 * g + 3]);
    }

    // ---- PV (swapped): O^T += V^T x P^T, kv chunks t of 16 ----
#pragma unroll
    for (int t = 0; t < 4; ++t) {
      const int c = t >> 1, ks = t & 1;
      const unsigned o0 = pk[c][4 * ks + 0], o1 = pk[c][4 * ks + 1];
      const unsigned o2 = pk[c][4 * ks + 2], o3 = pk[c][4 * ks + 3];
      const unsigned e0 = (unsigned)__shfl_xor((int)o0, 32, 64);
      const unsigned e1 = (unsigned)__shfl_xor((int)o1, 32, 64);
      const unsigned e2 = (unsigned)__shfl_xor((int)o2, 32, 64);
      const unsigned e3 = (unsigned)__shfl_xor((int)o3, 32, 64);
      union { unsigned u[4]; bf16x8 v; } pb;
      pb.u[0] = hi ? e2 : o0;
      pb.u[1] = hi ? e3 : o1;
      pb.u[2] = hi ? o2 : e0;
      pb.u[3] = hi ? o3 : e1;
      const int vch = (2 * t + hi) ^ (q5 & 7);
      const bf16x8 vf0 = *(const bf16x8*)((const char*)&vlds[cur][0] + q5 * 128 + vch * 16);
      const bf16x8 vf1 = *(const bf16x8*)((const char*)&vlds[cur][0] + (32 + q5) * 128 + vch * 16);
      __builtin_amdgcn_s_setprio(1);
      oacc0 = __builtin_amdgcn_mfma_f32_32x32x16_bf16(vf0, pb.v, oacc0, 0, 0, 0);
      oacc1 = __builtin_amdgcn_mfma_f32_32x32x16_bf16(vf1, pb.v, oacc1, 0, 0, 0);
      __builtin_amdgcn_s_setprio(0);
    }

    // ---- phase A -> B transition ----
    if (i == nA - 1) {
      flush(qrow);
      qt = qtB;
      qrow = qt * 64 + w * 32 + q5;
#pragma unroll
      for (int d = 0; d < 4; ++d)
        qf[d] = *(const bf16x8*)&qw[qkbase + (size_t)qrow * DHEAD + d * 16 + hi * 8];
#pragma unroll
      for (int r = 0; r < 16; ++r) { oacc0[r] = 0.f; oacc1[r] = 0.f; }
      mrun = -1e30f;
      lrun = 0.f;
    }
    // one barrier per iter: drains prefetch (vmcnt) + guards buffer reuse
    __syncthreads();
  }

  flush(qrow);
}

extern "C" void kernel_launch(void* const* d_in, const int* in_sizes, int n_in,
                              void* d_out, int out_size, void* d_ws, size_t ws_size,
                              hipStream_t stream) {
  (void)in_sizes; (void)n_in; (void)out_size;
  if (ws_size < (size_t)67108864) return;  // need 64 MB scratch

  const float* query = (const float*)d_in[0];
  const float* key_  = (const float*)d_in[1];
  const float* value = (const float*)d_in[2];
  // d_in[3] = mask (tril) — causality is hardcoded
  const float* Wq = (const float*)d_in[4];
  const float* bq = (const float*)d_in[5];
  const float* Wk = (const float*)d_in[6];
  const float* bk = (const float*)d_in[7];
  const float* Wv = (const float*)d_in[8];
  const float* bv = (const float*)d_in[9];
  const float* Wo = (const float*)d_in[10];
  const float* bo = (const float*)d_in[11];

  char* ws = (char*)d_ws;
  unsigned short* xp = (unsigned short*)(ws);              // [3][4096][1024] bf16
  unsigned short* wp = (unsigned short*)(ws + 25165824);   // [3][1024][1024] bf16
  unsigned short* wo = (unsigned short*)(ws + 31457280);   // [1024][1024] bf16
  unsigned short* qws = (unsigned short*)(ws + 33554432);  // [32][2048][64] bf16
  unsigned short* kws = (unsigned short*)(ws + 41943040);  // [32][2048][64] bf16
  unsigned short* vtw = (unsigned short*)(ws + 50331648);  // [32][64][2048] bf16
  unsigned short* x2 = (unsigned short*)(ws + 58720256);   // [4096][1024] bf16

  cvt_all_kernel<<<16384, 256, 0, stream>>>(query, key_, value, Wq, Wk, Wv, Wo, xp, wp, wo);

  gemm_bt<0><<<dim3(32, 8, 3), 256, 0, stream>>>(xp, wp, bq, bk, bv, qws, kws, vtw, nullptr);
  attn_kernel<<<dim3(32, 16), 128, 0, stream>>>(qws, kws, vtw, x2);
  gemm_bt<1><<<dim3(32, 8, 1), 256, 0, stream>>>(x2, wo, bo, bo, bo, nullptr, nullptr, nullptr,
                                                 (float*)d_out);
}

// Round 6
// 131.635 us; speedup vs baseline: 1.2663x; 1.2663x over previous
//
#include <hip/hip_runtime.h>
#include <stdint.h>

#define S_LEN 2048
#define BATCH 2
#define DMODEL 1024
#define NHEAD 16
#define DHEAD 64
// softmax scale folded into Q projection, in exp2 domain: 1/8 * log2(e)
#define QSCALE 0.18033688011112042f

typedef float f32x4 __attribute__((ext_vector_type(4)));
typedef float f32x16 __attribute__((ext_vector_type(16)));
typedef __bf16 bf16x8 __attribute__((ext_vector_type(8)));

#if __has_builtin(__builtin_amdgcn_exp2f)
#define EXP2(x) __builtin_amdgcn_exp2f(x)
#else
#define EXP2(x) exp2f(x)
#endif

__device__ __forceinline__ unsigned short f2bf(float f) {
  union { float f; unsigned int u; } v;
  v.f = f;
  unsigned int u = v.u;
  return (unsigned short)((u + 0x7fffu + ((u >> 16) & 1u)) >> 16);
}

__device__ __forceinline__ unsigned pk2(float lo, float hi_) {
  union { __bf16 h[2]; unsigned u; } c;
  c.h[0] = (__bf16)lo; c.h[1] = (__bf16)hi_;
  return c.u;
}

__device__ __forceinline__ void gld16(const void* g, void* l) {
  __builtin_amdgcn_global_load_lds((__attribute__((address_space(1))) void*)(g),
                                   (__attribute__((address_space(3))) void*)(l),
                                   16, 0, 0);
}

// ---------------- fp32 -> bf16 pack (all 7 tensors, one launch) ----------------
__global__ void cvt_all_kernel(const float* __restrict__ q, const float* __restrict__ k,
                               const float* __restrict__ v, const float* __restrict__ wq,
                               const float* __restrict__ wk, const float* __restrict__ wv,
                               const float* __restrict__ wosrc, unsigned short* __restrict__ xp,
                               unsigned short* __restrict__ wp, unsigned short* __restrict__ wo) {
  const int b = blockIdx.x;
  const float* src;
  unsigned short* dst;
  if (b < 12288) {
    const int z = b >> 12;
    const int local = b & 4095;
    src = (z == 0 ? q : (z == 1 ? k : v)) + (size_t)local * 1024;
    dst = xp + (size_t)z * 4194304 + (size_t)local * 1024;
  } else {
    const int z = (b - 12288) >> 10;
    const int local = (b - 12288) & 1023;
    src = (z == 0 ? wq : (z == 1 ? wk : (z == 2 ? wv : wosrc))) + (size_t)local * 1024;
    dst = (z < 3 ? wp + (size_t)z * 1048576 : wo) + (size_t)local * 1024;
  }
  const int i = threadIdx.x * 4;
  const float4 val = *(const float4*)(src + i);
  ushort4 o;
  o.x = f2bf(val.x); o.y = f2bf(val.y); o.z = f2bf(val.z); o.w = f2bf(val.w);
  *(ushort4*)(dst + i) = o;
}

// ---------------- GEMM: C[m,n] = sum_k A[m,k]*W[n,k] (+bias) ----------------
template <int MODE>
__global__ __launch_bounds__(256, 2) void gemm_bt(
    const unsigned short* __restrict__ Abase,
    const unsigned short* __restrict__ Wbase,
    const float* __restrict__ bias0, const float* __restrict__ bias1,
    const float* __restrict__ bias2,
    unsigned short* __restrict__ qw, unsigned short* __restrict__ kw,
    unsigned short* __restrict__ vtw, float* __restrict__ outp) {
  constexpr int M = S_LEN * BATCH;  // 4096
  constexpr int N = DMODEL;         // 1024
  constexpr int K = DMODEL;         // 1024
  __shared__ unsigned short At[128 * 32];
  __shared__ unsigned short Bt[128 * 32];

  const int m0 = blockIdx.x * 128;
  const int n0 = blockIdx.y * 128;
  const int z = (MODE == 0) ? blockIdx.z : 0;
  const unsigned short* A = Abase + (size_t)z * M * K;
  const unsigned short* W = Wbase + (size_t)z * N * K;
  const float* bias = (z == 0 ? bias0 : (z == 1 ? bias1 : bias2));

  const int tid = threadIdx.x;
  const int w = tid >> 6, l = tid & 63;
  const int wr = w >> 1, wc = w & 1;
  const int lr = l & 15, lg = l >> 4;

  const int srow = tid >> 2;       // 0..63
  const int scol = (tid & 3) * 8;  // element col within 32-wide k tile

  f32x4 acc[4][4] = {};

  for (int k0 = 0; k0 < K; k0 += 32) {
    {
      const unsigned short* ga0 = A + (size_t)(m0 + srow) * K + k0 + scol;
      const unsigned short* ga1 = A + (size_t)(m0 + 64 + srow) * K + k0 + scol;
      const unsigned short* gb0 = W + (size_t)(n0 + srow) * K + k0 + scol;
      const unsigned short* gb1 = W + (size_t)(n0 + 64 + srow) * K + k0 + scol;
      char* la = (char*)At + w * 1024;
      char* lb = (char*)Bt + w * 1024;
      gld16(ga0, la);
      gld16(ga1, la + 4096);
      gld16(gb0, lb);
      gld16(gb1, lb + 4096);
    }
    __syncthreads();
    bf16x8 af[4], bfr[4];
#pragma unroll
    for (int mt = 0; mt < 4; ++mt)
      af[mt] = *(const bf16x8*)&At[(wr * 64 + mt * 16 + lr) * 32 + lg * 8];
#pragma unroll
    for (int nt = 0; nt < 4; ++nt)
      bfr[nt] = *(const bf16x8*)&Bt[(wc * 64 + nt * 16 + lr) * 32 + lg * 8];
#pragma unroll
    for (int mt = 0; mt < 4; ++mt)
#pragma unroll
      for (int nt = 0; nt < 4; ++nt)
        acc[mt][nt] = __builtin_amdgcn_mfma_f32_16x16x32_bf16(af[mt], bfr[nt], acc[mt][nt], 0, 0, 0);
    __syncthreads();
  }

#pragma unroll
  for (int mt = 0; mt < 4; ++mt) {
#pragma unroll
    for (int nt = 0; nt < 4; ++nt) {
#pragma unroll
      for (int r = 0; r < 4; ++r) {
        const int gm = m0 + wr * 64 + mt * 16 + lg * 4 + r;
        const int gn = n0 + wc * 64 + nt * 16 + lr;
        float v = acc[mt][nt][r] + bias[gn];
        if (MODE == 1) {
          outp[(size_t)gm * N + gn] = v;
        } else {
          if (z == 0) v *= QSCALE;  // softmax scale + log2e (exp2-domain softmax)
          const int s = gm >> 1, bb = gm & 1;
          const int h = gn >> 6, dk = gn & 63;
          const int bh = bb * NHEAD + h;
          const unsigned short bv_ = f2bf(v);
          if (z == 0)
            qw[((size_t)bh * S_LEN + s) * DHEAD + dk] = bv_;
          else if (z == 1)
            kw[((size_t)bh * S_LEN + s) * DHEAD + dk] = bv_;
          else
            vtw[((size_t)bh * DHEAD + dk) * S_LEN + s] = bv_;
        }
      }
    }
  }
}

// ---------------- causal flash attention, swapped-operand 32x32 MFMA ----------------
// Block (bh, x): 4 waves. Processes q-tiles qtA=31-x then qtB=x (33 kv-tiles total).
// Wave-pairs split kv: pair0 = even tiles, pair1 = odd tiles; in-LDS m/l merge per phase.
// Every block: exactly 17 superiters; 512 blocks x 4 waves = 2 waves/SIMD. bh-major grid
// pins each head's K/V to one XCD's L2.
__global__ __launch_bounds__(256) void attn_kernel(
    const unsigned short* __restrict__ qw, const unsigned short* __restrict__ kw,
    const unsigned short* __restrict__ vtw, unsigned short* __restrict__ x2) {
  __shared__ unsigned short klds[2][8192];  // [buf][2 tiles x 4KB], XOR-swizzled 16B chunks
  __shared__ unsigned short vlds[2][8192];
  __shared__ float mlscr[2][64][2];

  const int bh = blockIdx.x;   // 0..31 (XCD = bh%8)
  const int xq = blockIdx.y;   // 0..15
  const int bb = bh >> 4, h = bh & 15;
  const int tid = threadIdx.x;
  const int w = tid >> 6, l = tid & 63;
  const int q5 = l & 31, hi = l >> 5;
  const int pair = w >> 1, wh = w & 1;

  const size_t qkbase = (size_t)bh * S_LEN * DHEAD;
  const size_t vbase = (size_t)bh * DHEAD * S_LEN;

  const int qtA = 31 - xq, qtB = xq;
  const int nA = qtA + 1, nB = qtB + 1;
  const int nsA = (nA + 1) >> 1;
  const int nsTot = nsA + ((nB + 1) >> 1);

  auto stage = [&](int kt0, int kt1, int b) {
#pragma unroll
    for (int r = 0; r < 4; ++r) {
      const int kt = (r >= 2) ? kt1 : kt0;  // tile boundary aligns with r boundary
      const int idx = (r * 256 + tid) & 511;
      const int row = idx >> 3;
      const int sw = (idx & 7) ^ (row & 7);
      gld16(kw + qkbase + (size_t)(kt * 64 + row) * DHEAD + sw * 8,
            (char*)&klds[b][0] + r * 4096 + w * 1024);
      gld16(vtw + vbase + (size_t)row * S_LEN + kt * 64 + sw * 8,
            (char*)&vlds[b][0] + r * 4096 + w * 1024);
    }
  };

  // ---- phase state ----
  int qt = qtA;
  int qrow = qt * 64 + wh * 32 + q5;
  bf16x8 qf[4];
#pragma unroll
  for (int d = 0; d < 4; ++d)
    qf[d] = *(const bf16x8*)&qw[qkbase + (size_t)qrow * DHEAD + d * 16 + hi * 8];

  f32x16 oacc0, oacc1;  // O^T[d = crow(r,hi) + 32*dh][q = q5]
#pragma unroll
  for (int r = 0; r < 16; ++r) { oacc0[r] = 0.f; oacc1[r] = 0.f; }
  float mrun = -1e30f, lrun = 0.f;

  stage(0, 1, 0);  // nA >= 17, so tiles 0,1 both valid
  __syncthreads();

  for (int s = 0; s < nsTot; ++s) {
    const int cur = s & 1;
    // ---- prefetch next superiter's tile pair ----
    if (s + 1 < nsTot) {
      int t0, lim;
      if (s + 1 < nsA) { t0 = 2 * (s + 1); lim = nA; }
      else { t0 = 2 * (s + 1 - nsA); lim = nB; }
      const int k1 = (t0 + 1 < lim) ? t0 + 1 : lim - 1;
      stage(t0, k1, cur ^ 1);
    }

    const bool phA = (s < nsA);
    const int myt = (phA ? 2 * s : 2 * (s - nsA)) + pair;
    const int lim = phA ? nA : nB;

    if (myt < lim) {
      const int kt = myt;
      const char* kb = (const char*)&klds[cur][0] + pair * 8192;
      const char* vb = (const char*)&vlds[cur][0] + pair * 8192;

      // ---- QK^T (swapped): S^T[kv][q] ----
      f32x16 scA, scB;
#pragma unroll
      for (int r = 0; r < 16; ++r) { scA[r] = 0.f; scB[r] = 0.f; }
      __builtin_amdgcn_s_setprio(1);
#pragma unroll
      for (int d = 0; d < 4; ++d) {
        const int ch = (2 * d + hi) ^ (q5 & 7);
        const bf16x8 kfA = *(const bf16x8*)(kb + q5 * 128 + ch * 16);
        const bf16x8 kfB = *(const bf16x8*)(kb + (32 + q5) * 128 + ch * 16);
        scA = __builtin_amdgcn_mfma_f32_32x32x16_bf16(kfA, qf[d], scA, 0, 0, 0);
        scB = __builtin_amdgcn_mfma_f32_32x32x16_bf16(kfB, qf[d], scB, 0, 0, 0);
      }
      __builtin_amdgcn_s_setprio(0);

      if (kt == qt) {  // causal mask on diagonal tile
        const int qloc = wh * 32 + q5;
#pragma unroll
        for (int r = 0; r < 16; ++r) {
          const int kv = (r & 3) + 8 * (r >> 2) + 4 * hi;
          if (kv > qloc) scA[r] = -1e9f;
          if (kv + 32 > qloc) scB[r] = -1e9f;
        }
      }

      // ---- online softmax (exp2 domain), tree reductions ----
      float mx[8];
#pragma unroll
      for (int j = 0; j < 8; ++j)
        mx[j] = fmaxf(fmaxf(scA[j], scA[j + 8]), fmaxf(scB[j], scB[j + 8]));
#pragma unroll
      for (int j = 0; j < 4; ++j) mx[j] = fmaxf(mx[j], mx[j + 4]);
      float tmax = fmaxf(fmaxf(mx[0], mx[1]), fmaxf(mx[2], mx[3]));
      tmax = fmaxf(tmax, __shfl_xor(tmax, 32, 64));
      const float mnew = fmaxf(mrun, tmax);
      const float resc = EXP2(mrun - mnew);
      mrun = mnew;
#pragma unroll
      for (int r = 0; r < 16; ++r) scA[r] = EXP2(scA[r] - mnew);
#pragma unroll
      for (int r = 0; r < 16; ++r) scB[r] = EXP2(scB[r] - mnew);
      float sm[8];
#pragma unroll
      for (int j = 0; j < 8; ++j)
        sm[j] = (scA[j] + scA[j + 8]) + (scB[j] + scB[j + 8]);
#pragma unroll
      for (int j = 0; j < 4; ++j) sm[j] += sm[j + 4];
      float rsum = (sm[0] + sm[1]) + (sm[2] + sm[3]);
      rsum += __shfl_xor(rsum, 32, 64);
      lrun = lrun * resc + rsum;
#pragma unroll
      for (int r = 0; r < 16; ++r) { oacc0[r] *= resc; oacc1[r] *= resc; }

      // ---- P^T B-frags in-register ----
      unsigned pk[2][8];
#pragma unroll
      for (int g = 0; g < 4; ++g) {
        pk[0][2 * g]     = pk2(scA[4 * g],     scA[4 * g + 1]);
        pk[0][2 * g + 1] = pk2(scA[4 * g + 2], scA[4 * g + 3]);
        pk[1][2 * g]     = pk2(scB[4 * g],     scB[4 * g + 1]);
        pk[1][2 * g + 1] = pk2(scB[4 * g + 2], scB[4 * g + 3]);
      }

      // ---- PV (swapped): O^T += V^T x P^T ----
#pragma unroll
      for (int t = 0; t < 4; ++t) {
        const int c = t >> 1, ks = t & 1;
        const unsigned o0 = pk[c][4 * ks + 0], o1 = pk[c][4 * ks + 1];
        const unsigned o2 = pk[c][4 * ks + 2], o3 = pk[c][4 * ks + 3];
        // single-shfl-per-word exchange: hi=0 needs partner o0/o1, hi=1 needs o2/o3
        const unsigned ea = (unsigned)__shfl_xor((int)(hi ? o0 : o2), 32, 64);
        const unsigned eb = (unsigned)__shfl_xor((int)(hi ? o1 : o3), 32, 64);
        union { unsigned u[4]; bf16x8 v; } pb;
        pb.u[0] = hi ? ea : o0;
        pb.u[1] = hi ? eb : o1;
        pb.u[2] = hi ? o2 : ea;
        pb.u[3] = hi ? o3 : eb;
        const int vch = (2 * t + hi) ^ (q5 & 7);
        const bf16x8 vf0 = *(const bf16x8*)(vb + q5 * 128 + vch * 16);
        const bf16x8 vf1 = *(const bf16x8*)(vb + (32 + q5) * 128 + vch * 16);
        __builtin_amdgcn_s_setprio(1);
        oacc0 = __builtin_amdgcn_mfma_f32_32x32x16_bf16(vf0, pb.v, oacc0, 0, 0, 0);
        oacc1 = __builtin_amdgcn_mfma_f32_32x32x16_bf16(vf1, pb.v, oacc1, 0, 0, 0);
        __builtin_amdgcn_s_setprio(0);
      }
    }

    // ---- phase end: cross-pair merge + flush (pair0 writes output) ----
    if (s == nsA - 1 || s == nsTot - 1) {
      __syncthreads();  // all compute on klds[cur] done; scratch = klds[cur]
      float* scr = (float*)&klds[cur][0];  // 4096 floats = 2 waves x 64 lanes x 32
      const int kx = l & 7;
      if (pair == 1) {
        f32x4* d4 = (f32x4*)(scr + (size_t)(wh * 64 + l) * 32);
#pragma unroll
        for (int c = 0; c < 4; ++c) {
          f32x4 ch_;
#pragma unroll
          for (int j = 0; j < 4; ++j) ch_[j] = oacc0[c * 4 + j];
          d4[c ^ kx] = ch_;
        }
#pragma unroll
        for (int c = 0; c < 4; ++c) {
          f32x4 ch_;
#pragma unroll
          for (int j = 0; j < 4; ++j) ch_[j] = oacc1[c * 4 + j];
          d4[(4 + c) ^ kx] = ch_;
        }
        mlscr[wh][l][0] = mrun;
        mlscr[wh][l][1] = lrun;
      }
      __syncthreads();
      if (pair == 0) {
        const f32x4* s4 = (const f32x4*)(scr + (size_t)(wh * 64 + l) * 32);
        const float m1 = mlscr[wh][l][0], l1 = mlscr[wh][l][1];
        const float ms = fmaxf(mrun, m1);
        const float a0 = EXP2(mrun - ms), a1 = EXP2(m1 - ms);
        const float lm = lrun * a0 + l1 * a1;
        const float invl = 1.0f / lm;
        const size_t obase = ((size_t)qrow * BATCH + bb) * DMODEL + h * DHEAD;
#pragma unroll
        for (int g = 0; g < 4; ++g) {
          const f32x4 c0 = s4[g ^ kx];
          const f32x4 c1 = s4[(4 + g) ^ kx];
          ushort4 s0, s1;
          s0.x = f2bf((oacc0[4 * g + 0] * a0 + c0[0] * a1) * invl);
          s0.y = f2bf((oacc0[4 * g + 1] * a0 + c0[1] * a1) * invl);
          s0.z = f2bf((oacc0[4 * g + 2] * a0 + c0[2] * a1) * invl);
          s0.w = f2bf((oacc0[4 * g + 3] * a0 + c0[3] * a1) * invl);
          s1.x = f2bf((oacc1[4 * g + 0] * a0 + c1[0] * a1) * invl);
          s1.y = f2bf((oacc1[4 * g + 1] * a0 + c1[1] * a1) * invl);
          s1.z = f2bf((oacc1[4 * g + 2] * a0 + c1[2] * a1) * invl);
          s1.w = f2bf((oacc1[4 * g + 3] * a0 + c1[3] * a1) * invl);
          const int d0 = 8 * g + 4 * hi;
          *(ushort4*)(x2 + obase + d0) = s0;
          *(ushort4*)(x2 + obase + 32 + d0) = s1;
        }
      }
      if (s == nsA - 1) {  // switch to phase B (q-tile qtB)
        qt = qtB;
        qrow = qt * 64 + wh * 32 + q5;
#pragma unroll
        for (int d = 0; d < 4; ++d)
          qf[d] = *(const bf16x8*)&qw[qkbase + (size_t)qrow * DHEAD + d * 16 + hi * 8];
#pragma unroll
        for (int r = 0; r < 16; ++r) { oacc0[r] = 0.f; oacc1[r] = 0.f; }
        mrun = -1e30f;
        lrun = 0.f;
      }
    }
    __syncthreads();  // drains prefetch + guards buffer swap
  }
}

extern "C" void kernel_launch(void* const* d_in, const int* in_sizes, int n_in,
                              void* d_out, int out_size, void* d_ws, size_t ws_size,
                              hipStream_t stream) {
  (void)in_sizes; (void)n_in; (void)out_size;
  if (ws_size < (size_t)67108864) return;  // need 64 MB scratch

  const float* query = (const float*)d_in[0];
  const float* key_  = (const float*)d_in[1];
  const float* value = (const float*)d_in[2];
  // d_in[3] = mask (tril) — causality is hardcoded
  const float* Wq = (const float*)d_in[4];
  const float* bq = (const float*)d_in[5];
  const float* Wk = (const float*)d_in[6];
  const float* bk = (const float*)d_in[7];
  const float* Wv = (const float*)d_in[8];
  const float* bv = (const float*)d_in[9];
  const float* Wo = (const float*)d_in[10];
  const float* bo = (const float*)d_in[11];

  char* ws = (char*)d_ws;
  unsigned short* xp = (unsigned short*)(ws);              // [3][4096][1024] bf16
  unsigned short* wp = (unsigned short*)(ws + 25165824);   // [3][1024][1024] bf16
  unsigned short* wo = (unsigned short*)(ws + 31457280);   // [1024][1024] bf16
  unsigned short* qws = (unsigned short*)(ws + 33554432);  // [32][2048][64] bf16
  unsigned short* kws = (unsigned short*)(ws + 41943040);  // [32][2048][64] bf16
  unsigned short* vtw = (unsigned short*)(ws + 50331648);  // [32][64][2048] bf16
  unsigned short* x2 = (unsigned short*)(ws + 58720256);   // [4096][1024] bf16

  cvt_all_kernel<<<16384, 256, 0, stream>>>(query, key_, value, Wq, Wk, Wv, Wo, xp, wp, wo);

  gemm_bt<0><<<dim3(32, 8, 3), 256, 0, stream>>>(xp, wp, bq, bk, bv, qws, kws, vtw, nullptr);
  attn_kernel<<<dim3(32, 16), 256, 0, stream>>>(qws, kws, vtw, x2);
  gemm_bt<1><<<dim3(32, 8, 1), 256, 0, stream>>>(x2, wo, bo, bo, bo, nullptr, nullptr, nullptr,
                                                 (float*)d_out);
}